// Round 18
// baseline (87.201 us; speedup 1.0000x reference)
//
#include <hip/hip_runtime.h>

typedef unsigned short u16;
typedef __attribute__((ext_vector_type(8))) short bf16x8;
typedef __attribute__((ext_vector_type(8))) unsigned short u16x8;
typedef __attribute__((ext_vector_type(4))) float f32x4;

#define NROWS 131072

static __device__ __forceinline__ u16 f2bf(float f) {
  unsigned u = __float_as_uint(f);
  u += 0x7fffu + ((u >> 16) & 1u);   // RNE (prep-path only)
  return (u16)(u >> 16);
}
static __device__ __forceinline__ float bf2f(u16 v) {
  return __uint_as_float(((unsigned)v) << 16);
}
// HW packed RNE convert: low16 = bf16(lo), high16 = bf16(hi)
static __device__ __forceinline__ unsigned cvtpk(float lo, float hi) {
  unsigned r;
  asm("v_cvt_pk_bf16_f32 %0, %1, %2" : "=v"(r) : "v"(lo), "v"(hi));
  return r;
}
// fast reciprocal (v_rcp_f32, ~1e-7 rel err — fine vs 2% threshold)
static __device__ __forceinline__ float frcp(float x) {
  float r;
  asm("v_rcp_f32 %0, %1" : "=v"(r) : "v"(x));
  return r;
}
static __device__ __forceinline__ float tanh_f(float x) {
  x = fminf(fmaxf(x, -15.f), 15.f);
  const float t = __expf(2.f * x);
  return (t - 1.f) * frcp(t + 1.f);
}

// ---------------- prep kernels ----------------

__global__ void k_prep_wc(const float* __restrict__ W0,
                          const float* __restrict__ W1,
                          u16* __restrict__ wcT) {
  __shared__ float lw1[128 * 128];
  const int t = threadIdx.x;
  for (int i = t; i < 128 * 128; i += 256) lw1[i] = W1[i];
  __syncthreads();
  const int c = t & 127;
  for (int kk = (t >> 7); kk < 8; kk += 2) {
    const int k = blockIdx.x * 8 + kk;
    const float* w0r = W0 + k * 128;
    float a = 0.f;
#pragma unroll 8
    for (int j = 0; j < 128; j++) a = fmaf(w0r[j], lw1[j * 128 + c], a);
    wcT[c * 256 + k] = f2bf(a);
  }
}

__global__ void k_prep_wh(const float* __restrict__ Wg, const float* __restrict__ Wf,
                          const float* __restrict__ Wh, const float* __restrict__ Wt,
                          u16* __restrict__ whT,
                          const float* __restrict__ bg, const float* __restrict__ bf_,
                          const float* __restrict__ bh, const float* __restrict__ bt,
                          float* __restrict__ biasc, float* __restrict__ gstatR) {
  const int idx = blockIdx.x * 256 + threadIdx.x;  // 65536 total
  const int col = idx >> 7, k = idx & 127;
  const int hh = col >> 7, c = col & 127;
  const float* W = hh == 0 ? Wg : hh == 1 ? Wf : hh == 2 ? Wh : Wt;
  whT[col * 128 + k] = f2bf(W[k * 128 + c]);
  if (blockIdx.x < 32) gstatR[blockIdx.x * 256 + threadIdx.x] = 0.f;  // 32 replicas
  if (blockIdx.x == 32) {
    for (int i = threadIdx.x; i < 512; i += 256) {
      const int h2 = i >> 7, c2 = i & 127;
      const float* s = h2 == 0 ? bg : h2 == 1 ? bf_ : h2 == 2 ? bh : bt;
      biasc[i] = s[c2];
    }
  }
}

// ---------------- pass 1: z = cat(x,h) @ Wc (bf16 z + column stats) ----------------
// ROUND-8 VERBATIM (known-pass, 57us, fastest gemm1 measured). Flat a[16]
// full-tile preload (NO asm pin — pin is the prime suspect in the r13-r15
// config-dependent failures and bought zero perf), launch_bounds (512,2),
// 4 row-tiles/block (grid 256).
__global__ __launch_bounds__(512, 2) void k_gemm1(
    const float* __restrict__ x, const float* __restrict__ h,
    const u16* __restrict__ wcT, u16* __restrict__ z,
    float* __restrict__ gstatR) {
  __shared__ u16 lwc[128 * 256];        // 64KB, XOR-swizzled
  __shared__ float lsum[128], lsq[128];
  const int t = threadIdx.x;
  const int w = t >> 6, lane = t & 63;
  const int c15 = lane & 15, g = lane >> 4;

  if (t < 128) lsum[t] = 0.f;
  else if (t < 256) lsq[t - 128] = 0.f;

  for (int q = t; q < 4096; q += 512) {   // stage WcT (16B chunks)
    const int c = q >> 5;
    const int dst = (q * 16) ^ ((c & 7) << 4);
    *(u16x8*)((char*)lwc + dst) = *(const u16x8*)((const char*)wcT + (size_t)q * 16);
  }
  __syncthreads();

  float sreg[8], qreg[8];
#pragma unroll
  for (int n = 0; n < 8; n++) { sreg[n] = 0.f; qreg[n] = 0.f; }

#pragma unroll 1
  for (int tile = 0; tile < 4; tile++) {
    const long row = (long)blockIdx.x * 512 + tile * 128 + w * 16 + c15;
    const float* xr = x + row * 128;
    const float* hr = h + row * 128;

    // flat preload: lane's FULL k-slice for this tile = 16 float4 (64 VGPR)
    float4 a[16];
#pragma unroll
    for (int i = 0; i < 8; i++) {
      const float* p = (i < 4 ? xr + i * 32 : hr + (i - 4) * 32) + g * 8;
      a[2 * i] = *(const float4*)p;
      a[2 * i + 1] = *(const float4*)(p + 4);
    }

    f32x4 acc[8];
#pragma unroll
    for (int n = 0; n < 8; n++) acc[n] = (f32x4){0.f, 0.f, 0.f, 0.f};

#pragma unroll
    for (int ks = 0; ks < 8; ks++) {
      union { bf16x8 v; unsigned u[4]; } U;
      U.u[0] = cvtpk(a[2 * ks].x, a[2 * ks].y);
      U.u[1] = cvtpk(a[2 * ks].z, a[2 * ks].w);
      U.u[2] = cvtpk(a[2 * ks + 1].x, a[2 * ks + 1].y);
      U.u[3] = cvtpk(a[2 * ks + 1].z, a[2 * ks + 1].w);
#pragma unroll
      for (int n = 0; n < 8; n++) {
        const int col = n * 16 + c15;
        const int inner = ((ks * 32 + g * 8) * 2) ^ ((col & 7) << 4);
        const bf16x8 bfr = *(const bf16x8*)((const char*)lwc + col * 512 + inner);
        acc[n] = __builtin_amdgcn_mfma_f32_16x16x32_bf16(U.v, bfr, acc[n], 0, 0, 0);
      }
    }

    // z write (bf16): C layout row=(lane>>4)*4+j, col=n*16+(lane&15)
    const long zrow = (long)blockIdx.x * 512 + tile * 128 + w * 16 + g * 4;
#pragma unroll
    for (int n = 0; n < 8; n++) {
      const int col = n * 16 + c15;
#pragma unroll
      for (int jp = 0; jp < 4; jp += 2) {
        const unsigned pk = cvtpk(acc[n][jp], acc[n][jp + 1]);
        z[(zrow + jp) * 128 + col] = (u16)pk;
        z[(zrow + jp + 1) * 128 + col] = (u16)(pk >> 16);
      }
      sreg[n] += acc[n][0] + acc[n][1] + acc[n][2] + acc[n][3];
      qreg[n] += acc[n][0] * acc[n][0] + acc[n][1] * acc[n][1] +
                 acc[n][2] * acc[n][2] + acc[n][3] * acc[n][3];
    }
  }

#pragma unroll
  for (int n = 0; n < 8; n++) {
    float s0 = sreg[n], q0 = qreg[n];
    s0 += __shfl_xor(s0, 16); s0 += __shfl_xor(s0, 32);
    q0 += __shfl_xor(q0, 16); q0 += __shfl_xor(q0, 32);
    if (g == 0) {
      atomicAdd(&lsum[n * 16 + c15], s0);
      atomicAdd(&lsq[n * 16 + c15], q0);
    }
  }
  __syncthreads();
  if (t < 128) {
    float* dst = gstatR + (blockIdx.x & 31) * 256;  // 32-way replicated stats
    atomicAdd(&dst[t], lsum[t]);
    atomicAdd(&dst[128 + t], lsq[t]);
  }
}

// ---------------- pass 2: BN+LeakyReLU+4 head GEMMs+gated combine ----------------
// ROUND-8 VERBATIM (pass, ~27us). grid 256, 8 waves, B-frags hoisted, fast math.
#define HEAD_NT 16
__global__ __launch_bounds__(512, 2) void k_head(
    const u16* __restrict__ z, const float* __restrict__ tvec,
    const u16* __restrict__ whT, const float* __restrict__ biasc,
    const float* __restrict__ gstatR, const float* __restrict__ gamma,
    const float* __restrict__ beta, float* __restrict__ out) {
  __shared__ u16 lwh[512 * 128];     // 128KB, staged once, read once (hoist)
  __shared__ u16 lzn[2][32 * 128];   // 2 x 8KB, swizzled
  __shared__ float ls[128], lb[128];
  const int t = threadIdx.x;
  const int w = t >> 6, lane = t & 63;
  const int c15 = lane & 15, g = lane >> 4;
  const int mw = w >> 2, cw = w & 3;

  const long tile0 = (long)blockIdx.x * HEAD_NT;
  const int zrow = t >> 4, zci = (t & 15) * 8;

  // prefetch first z chunk before the heavy WheadT stage
  u16x8 zreg = *(const u16x8*)(z + (tile0 * 32 + zrow) * 128 + zci);

  for (int q = t; q < 8192; q += 512) {   // stage WheadT (coalesced)
    const int col = q >> 4;
    const int dst = (q * 16) ^ ((col & 7) << 4);
    *(u16x8*)((char*)lwh + dst) = *(const u16x8*)((const char*)whT + (size_t)q * 16);
  }
  // BN finalize folded in: reduce 32 stat replicas
  if (t < 128) {
    float s = 0.f, q = 0.f;
#pragma unroll
    for (int r = 0; r < 32; r++) {
      s += gstatR[r * 256 + t];
      q += gstatR[r * 256 + 128 + t];
    }
    const float inv = 1.f / (float)NROWS;
    const float mean = s * inv;
    const float var = q * inv - mean * mean;
    const float sc = gamma[t] * rsqrtf(var + 1e-5f);
    ls[t] = sc;
    lb[t] = beta[t] - mean * sc;
  }

  float biasr[8];
#pragma unroll
  for (int fi = 0; fi < 8; fi++) {
    const int hh = fi >> 1, p = fi & 1;
    biasr[fi] = biasc[hh * 128 + cw * 32 + p * 16 + c15];
  }
  __syncthreads();  // lwh + ls/lb ready

  // hoist ALL B-fragments to registers: 32 x bf16x8 (128 VGPR) — static indices
  bf16x8 breg[32];
#pragma unroll
  for (int ks = 0; ks < 4; ks++) {
#pragma unroll
    for (int fi = 0; fi < 8; fi++) {
      const int hh = fi >> 1, p = fi & 1;
      const int colg = hh * 128 + cw * 32 + p * 16 + c15;
      const int binner = ((ks * 32 + g * 8) * 2) ^ ((colg & 7) << 4);
      breg[ks * 8 + fi] = *(const bf16x8*)((const char*)lwh + colg * 256 + binner);
    }
  }

  for (int it = 0; it < HEAD_NT; it++) {
    const long r0 = (tile0 + it) * 32;
    const int pb = it & 1;
    {  // BN + LeakyReLU -> bf16 -> swizzled LDS (dbuf)
      union { u16x8 v; unsigned u[4]; } Z;
#pragma unroll
      for (int e = 0; e < 8; e += 2) {
        const int k = zci + e;
        float f0 = bf2f(zreg[e]) * ls[k] + lb[k];
        float f1 = bf2f(zreg[e + 1]) * ls[k + 1] + lb[k + 1];
        f0 = f0 > 0.f ? f0 : 0.01f * f0;
        f1 = f1 > 0.f ? f1 : 0.01f * f1;
        Z.u[e >> 1] = cvtpk(f0, f1);
      }
      const int dst = (zrow * 256 + zci * 2) ^ ((zrow & 7) << 4);
      *(u16x8*)((char*)lzn[pb] + dst) = Z.v;
    }
    if (it < HEAD_NT - 1)  // prefetch next tile's z (issues before barrier)
      zreg = *(const u16x8*)(z + ((tile0 + it + 1) * 32 + zrow) * 128 + zci);
    const float4 tq = *(const float4*)(tvec + r0 + mw * 16 + g * 4);
    __syncthreads();  // zn[pb] written by all waves

    f32x4 acc[8];
#pragma unroll
    for (int fi = 0; fi < 8; fi++) acc[fi] = (f32x4){0.f, 0.f, 0.f, 0.f};
#pragma unroll
    for (int ks = 0; ks < 4; ks++) {
      const int rowl = mw * 16 + c15;
      const int ainner = ((ks * 32 + g * 8) * 2) ^ ((rowl & 7) << 4);
      const bf16x8 af = *(const bf16x8*)((const char*)lzn[pb] + rowl * 256 + ainner);
#pragma unroll
      for (int fi = 0; fi < 8; fi++)
        acc[fi] = __builtin_amdgcn_mfma_f32_16x16x32_bf16(af, breg[ks * 8 + fi], acc[fi], 0, 0, 0);
    }

#pragma unroll
    for (int j = 0; j < 4; j++) {
      const long row = r0 + mw * 16 + g * 4 + j;
      const float tv = tq[j];
#pragma unroll
      for (int p = 0; p < 2; p++) {
        const float ug = acc[0 + p][j] + biasr[0 + p];
        const float uf = acc[2 + p][j] + biasr[2 + p];
        const float uh = acc[4 + p][j] + biasr[4 + p];
        const float ut = acc[6 + p][j] + biasr[6 + p];
        const float gg = tanh_f(ug);
        const float hv = tanh_f(uh);
        const float sig = frcp(1.f + __expf(-(ut + uf) * tv));
        out[row * 128 + cw * 32 + p * 16 + c15] = hv + sig * (gg - hv);
      }
    }
  }
}

// ---------------- launch ----------------
extern "C" void kernel_launch(void* const* d_in, const int* in_sizes, int n_in,
                              void* d_out, int out_size, void* d_ws, size_t ws_size,
                              hipStream_t stream) {
  const float* x     = (const float*)d_in[0];
  const float* h     = (const float*)d_in[1];
  const float* tv    = (const float*)d_in[2];
  const float* W0    = (const float*)d_in[3];
  const float* W1    = (const float*)d_in[4];
  const float* gamma = (const float*)d_in[5];
  const float* beta  = (const float*)d_in[6];
  const float* Wg    = (const float*)d_in[7];
  const float* bg    = (const float*)d_in[8];
  const float* Wf    = (const float*)d_in[9];
  const float* bf_   = (const float*)d_in[10];
  const float* Wh    = (const float*)d_in[11];
  const float* bh    = (const float*)d_in[12];
  const float* Wt    = (const float*)d_in[13];
  const float* bt    = (const float*)d_in[14];

  char* ws = (char*)d_ws;
  const size_t OFF_Z    = 0;                       // 33554432
  const size_t OFF_WC   = 33554432;                // 65536
  const size_t OFF_WH   = OFF_WC + 65536;          // 131072
  const size_t OFF_BIAS = OFF_WH + 131072;         // 2048
  const size_t OFF_STAT = OFF_BIAS + 2048;         // 32*256*4
  u16*   zbuf  = (u16*)(ws + OFF_Z);
  u16*   wcT   = (u16*)(ws + OFF_WC);
  u16*   whT   = (u16*)(ws + OFF_WH);
  float* biasc = (float*)(ws + OFF_BIAS);
  float* gstat = (float*)(ws + OFF_STAT);

  hipLaunchKernelGGL(k_prep_wc, dim3(32),  dim3(256), 0, stream, W0, W1, wcT);
  hipLaunchKernelGGL(k_prep_wh, dim3(256), dim3(256), 0, stream,
                     Wg, Wf, Wh, Wt, whT, bg, bf_, bh, bt, biasc, gstat);
  hipLaunchKernelGGL(k_gemm1,   dim3(256), dim3(512), 0, stream, x, h, wcT, zbuf, gstat);
  hipLaunchKernelGGL(k_head,    dim3(256), dim3(512), 0, stream,
                     zbuf, tv, whT, biasc, gstat, gamma, beta, (float*)d_out);
}